// Round 19
// baseline (102.703 us; speedup 1.0000x reference)
//
#include <hip/hip_runtime.h>

typedef __bf16 bf16;
typedef __bf16 bf16x4 __attribute__((ext_vector_type(4)));
typedef __bf16 bf16x8 __attribute__((ext_vector_type(8)));
typedef float  f32x4  __attribute__((ext_vector_type(4)));

#define SCALE 0.17677669529663687f  // 32^-0.5

// ws layout (bytes)
#define XWIN_OFF  0                  // bf16 [64 b][64 win][64 tok][96 ch]
#define WQKVT_OFF 50331648           // bf16 [288][96] (q cols pre-scaled)
#define WOUTT_OFF 50386944           // bf16 [96][96] transposed
#define BIASC_OFF 50405376           // f32 [3 h][4 ni][4 w][64 lane][4 e] C-frag layout

#define CBAR() asm volatile("" ::: "memory")

// 16-lane (DPP row) all-reduce; ctrl must be a compile-time constant.
template <int CTRL>
__device__ __forceinline__ float dpp_mv(float x) {
    return __int_as_float(__builtin_amdgcn_update_dpp(
        0, __float_as_int(x), CTRL, 0xF, 0xF, true));
}
__device__ __forceinline__ float row16_max(float m) {
    m = fmaxf(m, dpp_mv<0xB1>(m));   // quad_perm [1,0,3,2]
    m = fmaxf(m, dpp_mv<0x4E>(m));   // quad_perm [2,3,0,1]
    m = fmaxf(m, dpp_mv<0x124>(m));  // row_ror:4
    m = fmaxf(m, dpp_mv<0x128>(m));  // row_ror:8
    return m;
}
__device__ __forceinline__ float row16_sum(float s) {
    s += dpp_mv<0xB1>(s);
    s += dpp_mv<0x4E>(s);
    s += dpp_mv<0x124>(s);
    s += dpp_mv<0x128>(s);
    return s;
}

// ---- im2win (blocks 0..511) + weight/bias prep (blocks 512..515)
__global__ __launch_bounds__(512)
void pre(const float* __restrict__ x, const float* __restrict__ wqkv,
         const float* __restrict__ pos, const float* __restrict__ wout,
         bf16* __restrict__ xwin, bf16* __restrict__ wqkvT,
         bf16* __restrict__ woutT, float* __restrict__ biasC)
{
    __shared__ bf16 xs[392 * 50];
    if (blockIdx.x < 512) {
        const int tid = threadIdx.x;
        const int b = blockIdx.x >> 3, wh = blockIdx.x & 7;
        const float* xb = x + (size_t)b * 96 * 3136 + wh * 7 * 56;
        bf16* xo = xwin + ((size_t)b * 64 + wh * 8) * 64 * 96;
        for (int c0 = 0; c0 < 96; c0 += 48) {
            if (c0) __syncthreads();
            for (int i = tid; i < 48 * 392; i += 512) {
                int c = i / 392, t = i - c * 392;
                xs[t * 50 + c] = (bf16)xb[(size_t)(c0 + c) * 3136 + t];
            }
            __syncthreads();
            for (int i = tid; i < 8 * 64 * 48; i += 512) {
                int c = i % 48;
                int wt = (i / 48) & 63;
                int win = i / (48 * 64);
                bf16 v = (bf16)0.f;
                if (wt < 49) v = xs[((wt / 7) * 56 + win * 7 + (wt % 7)) * 50 + c];
                xo[(win * 64 + wt) * 96 + c0 + c] = v;
            }
        }
    } else {
        int tid = (blockIdx.x - 512) * 512 + threadIdx.x;
        const int stride = 4 * 512;
        for (int i = tid; i < 288 * 96; i += stride) {
            int n = i / 96, c = i % 96;
            float v = wqkv[c * 288 + n];
            if (n < 96) v *= SCALE;
            wqkvT[i] = (bf16)v;
        }
        for (int i = tid; i < 96 * 96; i += stride) {
            int o = i / 96, c = i % 96;
            woutT[i] = (bf16)wout[c * 96 + o];
        }
        // biasC[h][ni][w][lane][e] at row=w*16+(lane>>4)*4+e, col=ni*16+(lane&15)
        for (int i = tid; i < 3 * 4 * 4 * 64 * 4; i += stride) {
            int e = i & 3, lane = (i >> 2) & 63, wv = (i >> 8) & 3, ni = (i >> 10) & 3, h = i >> 12;
            int row = wv * 16 + ((lane >> 4) << 2) + e;
            int col = ni * 16 + (lane & 15);
            float v;
            if (col >= 49) v = -1e30f;
            else if (row >= 49) v = 0.f;
            else {
                int ridx = ((col / 7) - (row / 7) + 6) * 13 + ((col % 7) - (row % 7) + 6);
                v = pos[ridx * 3 + h];
            }
            biasC[i] = v;
        }
    }
}

// One block (4 waves) per window. Operand-SWAPPED GEMMs (QKV, PV, proj):
// C-fragments land with 4 contiguous channels per lane -> packed b64/f128
// LDS writes instead of scalar scatter. All LDS read patterns unchanged.
// LDS 40448 B -> 4 blocks/CU. XCD swizzle blkId = b*64+ww*8+wh.
__global__ __launch_bounds__(256, 4)
void winattn(const bf16* __restrict__ xwin, const float* __restrict__ bout,
             const bf16* __restrict__ wqkvT, const bf16* __restrict__ woutT,
             const float* __restrict__ biasC, float* __restrict__ out)
{
    __shared__ __align__(16) unsigned char smem[40448];
    bf16* qall = (bf16*)(smem);          // [64 tok][104] (96 ch + pad)
    bf16* kall = (bf16*)(smem + 13312);  // [64 tok][104]
    bf16* vt   = (bf16*)(smem + 26624);  // [96 ch][72 tok]
    bf16* Ost  = (bf16*)(smem);          // overlay qall: [64 tok][104]
    float* fin = (float*)(smem + 13312); // [64 tok][104] f32, overlays kall+vt

    const int tid = threadIdx.x;
    const int w = tid >> 6, lane = tid & 63;
    const int lr = lane & 15, lk = lane >> 4;

    // ---- XCD write-combining decode
    const int blkraw = blockIdx.x;
    const int b  = blkraw >> 6;
    const int wh = blkraw & 7;
    const int ww = (blkraw >> 3) & 7;
    const int win = wh * 8 + ww;
    const int row0 = wh * 7, col0 = ww * 7;
    const bf16* xg = xwin + (size_t)(b * 64 + win) * 64 * 96;

    // ---- QKV (swapped): wave owns ni out-ch tiles (5,5,4,4 of 18);
    //      D^T[out][tok]: lane holds 4 contiguous out-ch for token lr.
    {
        bf16x8 xb[4][3];
#pragma unroll
        for (int mt = 0; mt < 4; ++mt)
#pragma unroll
            for (int k = 0; k < 3; ++k)
                xb[mt][k] = *(const bf16x8*)&xg[(mt * 16 + lr) * 96 + k * 32 + lk * 8];
        const int ni0  = (w < 2) ? w * 5 : 10 + (w - 2) * 4;
        const int ncnt = (w < 2) ? 5 : 4;
#pragma unroll
        for (int j = 0; j < 5; ++j) {
            if (j < ncnt) {
                const int ni = ni0 + j;
                f32x4 acc[4];
#pragma unroll
                for (int mt = 0; mt < 4; ++mt) acc[mt] = (f32x4){0.f, 0.f, 0.f, 0.f};
#pragma unroll
                for (int k = 0; k < 3; ++k) {
                    bf16x8 wa = *(const bf16x8*)&wqkvT[(ni * 16 + lr) * 96 + k * 32 + lk * 8];
#pragma unroll
                    for (int mt = 0; mt < 4; ++mt)
                        acc[mt] = __builtin_amdgcn_mfma_f32_16x16x32_bf16(wa, xb[mt][k], acc[mt], 0, 0, 0);
                }
                if (ni < 6) {
#pragma unroll
                    for (int mt = 0; mt < 4; ++mt) {
                        bf16x4 pk;
#pragma unroll
                        for (int e = 0; e < 4; ++e) pk[e] = (bf16)acc[mt][e];
                        *(bf16x4*)&qall[(mt * 16 + lr) * 104 + ni * 16 + lk * 4] = pk;
                    }
                } else if (ni < 12) {
#pragma unroll
                    for (int mt = 0; mt < 4; ++mt) {
                        bf16x4 pk;
#pragma unroll
                        for (int e = 0; e < 4; ++e) pk[e] = (bf16)acc[mt][e];
                        *(bf16x4*)&kall[(mt * 16 + lr) * 104 + (ni - 6) * 16 + lk * 4] = pk;
                    }
                } else {
                    // V -> vt[ch][tok]: rows differ per e, scalar writes
#pragma unroll
                    for (int mt = 0; mt < 4; ++mt)
#pragma unroll
                        for (int e = 0; e < 4; ++e)
                            vt[((ni - 12) * 16 + lk * 4 + e) * 72 + mt * 16 + lr] = (bf16)acc[mt][e];
                }
            }
        }
    }
    // prefetch head-0 bias C-frags (latency covered by barrier)
    f32x4 bias0[4], bias1[4], bias2[4];
#pragma unroll
    for (int ni = 0; ni < 4; ++ni)
        bias0[ni] = *(const f32x4*)&biasC[(size_t)((0 * 4 + ni) * 4 + w) * 256 + lane * 4];
    __syncthreads();   // B1

    // ---- read Q A-frags for all heads; then P may overlay own qall strip
    bf16x8 qa[3];
#pragma unroll
    for (int h = 0; h < 3; ++h)
        qa[h] = *(const bf16x8*)&qall[(w * 16 + lr) * 104 + h * 32 + lk * 8];
    CBAR();   // in-order DS pipe handles the WAR vs Pw writes

    bf16* Pw = (bf16*)(smem + w * 3328);   // [16][72] inside own qall strip

    f32x4 oacc[3][2];
#pragma unroll
    for (int h = 0; h < 3; ++h)
#pragma unroll
        for (int dt = 0; dt < 2; ++dt) oacc[h][dt] = (f32x4){0.f, 0.f, 0.f, 0.f};

#pragma unroll
    for (int h = 0; h < 3; ++h) {
        // S = Q@K^T + bias (bias is the C-operand); unswapped
        f32x4 sacc[4];
        const f32x4* bc = (h == 0) ? bias0 : (h == 1) ? bias1 : bias2;
#pragma unroll
        for (int ni = 0; ni < 4; ++ni) {
            bf16x8 kb = *(const bf16x8*)&kall[(ni * 16 + lr) * 104 + h * 32 + lk * 8];
            sacc[ni] = __builtin_amdgcn_mfma_f32_16x16x32_bf16(qa[h], kb, bc[ni], 0, 0, 0);
        }
        // prefetch next head's bias (covered by softmax+PV)
        if (h == 0) {
#pragma unroll
            for (int ni = 0; ni < 4; ++ni)
                bias1[ni] = *(const f32x4*)&biasC[(size_t)((1 * 4 + ni) * 4 + w) * 256 + lane * 4];
        } else if (h == 1) {
#pragma unroll
            for (int ni = 0; ni < 4; ++ni)
                bias2[ni] = *(const f32x4*)&biasC[(size_t)((2 * 4 + ni) * 4 + w) * 256 + lane * 4];
        }
        // softmax: 4 regs local + DPP 16-lane all-reduce; P normalized at write
#pragma unroll
        for (int e = 0; e < 4; ++e) {
            float s0 = sacc[0][e], s1 = sacc[1][e], s2 = sacc[2][e], s3 = sacc[3][e];
            float m = row16_max(fmaxf(fmaxf(s0, s1), fmaxf(s2, s3)));
            float p0 = __expf(s0 - m), p1 = __expf(s1 - m);
            float p2 = __expf(s2 - m), p3 = __expf(s3 - m);
            float s = row16_sum((p0 + p1) + (p2 + p3));
            float inv = __builtin_amdgcn_rcpf(s);
            int rl = lk * 4 + e;
            Pw[rl * 72 + lr]      = (bf16)(p0 * inv);
            Pw[rl * 72 + 16 + lr] = (bf16)(p1 * inv);
            Pw[rl * 72 + 32 + lr] = (bf16)(p2 * inv);
            Pw[rl * 72 + 48 + lr] = (bf16)(p3 * inv);
        }
        CBAR();
        // PV (swapped): O^T[d][q] = V^T @ P^T; same frag reads as before
#pragma unroll
        for (int kk = 0; kk < 2; ++kk) {
            bf16x8 pa = *(const bf16x8*)&Pw[lr * 72 + kk * 32 + lk * 8];
#pragma unroll
            for (int dt = 0; dt < 2; ++dt) {
                bf16x8 vb = *(const bf16x8*)&vt[(h * 32 + dt * 16 + lr) * 72 + kk * 32 + lk * 8];
                oacc[h][dt] = __builtin_amdgcn_mfma_f32_16x16x32_bf16(vb, pa, oacc[h][dt], 0, 0, 0);
            }
        }
        CBAR();
    }

    // ---- O -> Ost[tok][ch] (overlay qall, own strip): packed b64 writes.
    //      Swapped-PV C: lane holds 4 contiguous d for q-row lr.
#pragma unroll
    for (int h = 0; h < 3; ++h)
#pragma unroll
        for (int dt = 0; dt < 2; ++dt) {
            bf16x4 pk;
#pragma unroll
            for (int e = 0; e < 4; ++e) pk[e] = (bf16)oacc[h][dt][e];
            *(bf16x4*)&Ost[(w * 16 + lr) * 104 + h * 32 + dt * 16 + lk * 4] = pk;
        }
    __syncthreads();   // B2

    // ---- proj (swapped, pair-balanced): 24 (ni,mt) pairs, 6 per wave.
    //      fin^T[out][tok]: lane holds 4 contiguous out-ch for token lr -> float4.
    {
#pragma unroll
        for (int j = 0; j < 6; ++j) {
            const int p  = w * 6 + j;
            const int ni = p >> 2, mt = p & 3;
            f32x4 pacc = (f32x4){0.f, 0.f, 0.f, 0.f};
#pragma unroll
            for (int k = 0; k < 3; ++k) {
                bf16x8 wa = *(const bf16x8*)&woutT[(ni * 16 + lr) * 96 + k * 32 + lk * 8];
                bf16x8 ob = *(const bf16x8*)&Ost[(mt * 16 + lr) * 104 + k * 32 + lk * 8];
                pacc = __builtin_amdgcn_mfma_f32_16x16x32_bf16(wa, ob, pacc, 0, 0, 0);
            }
            float4 bo4 = *(const float4*)&bout[ni * 16 + lk * 4];
            float4 f;
            f.x = pacc[0] + bo4.x; f.y = pacc[1] + bo4.y;
            f.z = pacc[2] + bo4.z; f.w = pacc[3] + bo4.w;
            *(float4*)&fin[(mt * 16 + lr) * 104 + ni * 16 + lk * 4] = f;
        }
    }
    __syncthreads();   // B3

    // ---- store [b, c, H, W]; t = lane fixed, channel marches
    {
        const int t = lane;
        if (t < 49) {
            const int off = (row0 + t / 7) * 56 + col0 + t % 7;
            float* ob = out + (size_t)(b * 96 + w * 24) * 3136 + off;
            const float* fr = fin + t * 104 + w * 24;
#pragma unroll
            for (int j = 0; j < 24; ++j)
                ob[(size_t)j * 3136] = fr[j];
        }
    }
}

extern "C" void kernel_launch(void* const* d_in, const int* in_sizes, int n_in,
                              void* d_out, int out_size, void* d_ws, size_t ws_size,
                              hipStream_t stream) {
    const float* x    = (const float*)d_in[0];
    const float* wqkv = (const float*)d_in[1];
    const float* pos  = (const float*)d_in[2];
    const float* wout = (const float*)d_in[3];
    const float* bout = (const float*)d_in[4];
    float* outp = (float*)d_out;

    bf16*  xwin  = (bf16*)((char*)d_ws + XWIN_OFF);
    bf16*  wqkvT = (bf16*)((char*)d_ws + WQKVT_OFF);
    bf16*  woutT = (bf16*)((char*)d_ws + WOUTT_OFF);
    float* biasC = (float*)((char*)d_ws + BIASC_OFF);

    pre<<<dim3(516), dim3(512), 0, stream>>>(x, wqkv, pos, wout,
                                             xwin, wqkvT, woutT, biasC);
    winattn<<<dim3(4096), dim3(256), 0, stream>>>(xwin, bout, wqkvT, woutT,
                                                  biasC, outp);
}

// Round 20
// 79.312 us; speedup vs baseline: 1.2949x; 1.2949x over previous
//
#include <hip/hip_runtime.h>

typedef __bf16 bf16;
typedef __bf16 bf16x4 __attribute__((ext_vector_type(4)));
typedef __bf16 bf16x8 __attribute__((ext_vector_type(8)));
typedef float  f32x4  __attribute__((ext_vector_type(4)));

#define SCALE 0.17677669529663687f  // 32^-0.5

// ws layout (bytes) — xwin eliminated
#define WQKVT_OFF 0         // bf16 [288][96] (q cols pre-scaled)
#define WOUTT_OFF 55296     // bf16 [96][96] transposed
#define BIASC_OFF 73728     // f32 [3 h][4 ni][4 w][64 lane][4 e] C-frag layout

#define CBAR() asm volatile("" ::: "memory")

// 16-lane (DPP row) all-reduce; ctrl must be a compile-time constant.
template <int CTRL>
__device__ __forceinline__ float dpp_mv(float x) {
    return __int_as_float(__builtin_amdgcn_update_dpp(
        0, __float_as_int(x), CTRL, 0xF, 0xF, true));
}
__device__ __forceinline__ float row16_max(float m) {
    m = fmaxf(m, dpp_mv<0xB1>(m));   // quad_perm [1,0,3,2]
    m = fmaxf(m, dpp_mv<0x4E>(m));   // quad_perm [2,3,0,1]
    m = fmaxf(m, dpp_mv<0x124>(m));  // row_ror:4
    m = fmaxf(m, dpp_mv<0x128>(m));  // row_ror:8
    return m;
}
__device__ __forceinline__ float row16_sum(float s) {
    s += dpp_mv<0xB1>(s);
    s += dpp_mv<0x4E>(s);
    s += dpp_mv<0x124>(s);
    s += dpp_mv<0x128>(s);
    return s;
}

// ---- weight/bias prep only (tiny): 4 blocks x 512
__global__ __launch_bounds__(512)
void prep(const float* __restrict__ wqkv, const float* __restrict__ pos,
          const float* __restrict__ wout, bf16* __restrict__ wqkvT,
          bf16* __restrict__ woutT, float* __restrict__ biasC)
{
    int tid = blockIdx.x * 512 + threadIdx.x;
    const int stride = 4 * 512;
    for (int i = tid; i < 288 * 96; i += stride) {
        int n = i / 96, c = i % 96;
        float v = wqkv[c * 288 + n];
        if (n < 96) v *= SCALE;
        wqkvT[i] = (bf16)v;
    }
    for (int i = tid; i < 96 * 96; i += stride) {
        int o = i / 96, c = i % 96;
        woutT[i] = (bf16)wout[c * 96 + o];
    }
    // biasC[h][ni][w][lane][e] at row=w*16+(lane>>4)*4+e, col=ni*16+(lane&15)
    for (int i = tid; i < 3 * 4 * 4 * 64 * 4; i += stride) {
        int e = i & 3, lane = (i >> 2) & 63, wv = (i >> 8) & 3, ni = (i >> 10) & 3, h = i >> 12;
        int row = wv * 16 + ((lane >> 4) << 2) + e;
        int col = ni * 16 + (lane & 15);
        float v;
        if (col >= 49) v = -1e30f;
        else if (row >= 49) v = 0.f;
        else {
            int ridx = ((col / 7) - (row / 7) + 6) * 13 + ((col % 7) - (row % 7) + 6);
            v = pos[ridx * 3 + h];
        }
        biasC[i] = v;
    }
}

// One block (4 waves) per window, FUSED: stages its own x window (no xwin).
// QKV ownership ni = {w, w+4, w+8, w+12, (+16 if w<2)}; V tiles held in regs
// until xs (staged in vt-space) is dead. LDS 40448 B -> 4 blocks/CU.
// XCD swizzle blkId = b*64 + ww*8 + wh (same-row windows share an XCD).
__global__ __launch_bounds__(256, 4)
void winattn(const float* __restrict__ x, const float* __restrict__ bout,
             const bf16* __restrict__ wqkvT, const bf16* __restrict__ woutT,
             const float* __restrict__ biasC, float* __restrict__ out)
{
    __shared__ __align__(16) unsigned char smem[40448];
    bf16* qall = (bf16*)(smem);          // [64][104]
    bf16* kall = (bf16*)(smem + 13312);  // [64][104]
    bf16* vt   = (bf16*)(smem + 26624);  // [96][72] (after stage consumed)
    bf16* xs   = (bf16*)(smem + 26624);  // [64][108] staged window (overlay vt)
    bf16* Ost  = (bf16*)(smem);          // overlay qall
    float* fin = (float*)(smem + 13312); // [64][101] f32, overlays kall+vt

    const int tid = threadIdx.x;
    const int w = tid >> 6, lane = tid & 63;
    const int lr = lane & 15, lk = lane >> 4;

    // ---- XCD write-combining decode
    const int blkraw = blockIdx.x;
    const int b  = blkraw >> 6;
    const int wh = blkraw & 7;
    const int ww = (blkraw >> 3) & 7;
    const int row0 = wh * 7, col0 = ww * 7;

    // ---- stage x window -> xs[64][108] bf16 (zeros in pad rows)
    {
        const int t = lane;                 // token 0..63 (per wave, all tokens)
        const int c0 = (tid >> 6) * 24;     // wave's channel range
        const bool valid = t < 49;
        const int tr = valid ? t / 7 : 0, tc = valid ? t % 7 : 0;
        const float* xp = x + ((size_t)(b * 96 + c0)) * 3136
                            + (row0 + tr) * 56 + col0 + tc;
        bf16* xw = &xs[t * 108 + c0];
#pragma unroll
        for (int j = 0; j < 24; ++j) {
            float v = xp[(size_t)j * 3136];
            xw[j] = (bf16)(valid ? v : 0.f);
        }
    }
    __syncthreads();   // B0: xs ready

    // ---- QKV: wave w owns ni = {w, w+4, w+8, w+12} (+ w+16 if w<2)
    f32x4 vh0[4], vh1[4];   // V C-frags held until xs dead (static idx)
    {
        bf16x8 a[4][3];
#pragma unroll
        for (int mi = 0; mi < 4; ++mi)
#pragma unroll
            for (int k = 0; k < 3; ++k) {
                bf16x4 lo = *(const bf16x4*)&xs[(mi * 16 + lr) * 108 + k * 32 + lk * 8];
                bf16x4 hi = *(const bf16x4*)&xs[(mi * 16 + lr) * 108 + k * 32 + lk * 8 + 4];
                a[mi][k] = __builtin_shufflevector(lo, hi, 0, 1, 2, 3, 4, 5, 6, 7);
            }
        CBAR();

        auto compute = [&](int ni, f32x4 (&acc)[4]) {
#pragma unroll
            for (int mi = 0; mi < 4; ++mi) acc[mi] = (f32x4){0.f, 0.f, 0.f, 0.f};
#pragma unroll
            for (int k = 0; k < 3; ++k) {
                bf16x8 bb = *(const bf16x8*)&wqkvT[(ni * 16 + lr) * 96 + k * 32 + lk * 8];
#pragma unroll
                for (int mi = 0; mi < 4; ++mi)
                    acc[mi] = __builtin_amdgcn_mfma_f32_16x16x32_bf16(a[mi][k], bb, acc[mi], 0, 0, 0);
            }
        };
        auto writeQ = [&](int ni, f32x4 (&acc)[4]) {
#pragma unroll
            for (int mi = 0; mi < 4; ++mi)
#pragma unroll
                for (int e = 0; e < 4; ++e)
                    qall[(mi * 16 + lk * 4 + e) * 104 + ni * 16 + lr] = (bf16)acc[mi][e];
        };
        auto writeK = [&](int ni, f32x4 (&acc)[4]) {
#pragma unroll
            for (int mi = 0; mi < 4; ++mi)
#pragma unroll
                for (int e = 0; e < 4; ++e)
                    kall[(mi * 16 + lk * 4 + e) * 104 + (ni - 6) * 16 + lr] = (bf16)acc[mi][e];
        };

        f32x4 acc[4];
        compute(w, acc);          writeQ(w, acc);                 // j=0: Q
        compute(w + 4, acc);                                      // j=1: Q(w<2) or K
        if (w < 2) writeQ(w + 4, acc); else writeK(w + 4, acc);
        compute(w + 8, acc);      writeK(w + 8, acc);             // j=2: K
        compute(w + 12, vh0);                                     // j=3: V -> regs
        if (w < 2) compute(w + 16, vh1);                          // j=4: V -> regs
    }
    // prefetch head-0 bias C-frags (overlaps barrier)
    f32x4 bias0[4], bias1[4], bias2[4];
#pragma unroll
    for (int ni = 0; ni < 4; ++ni)
        bias0[ni] = *(const f32x4*)&biasC[(size_t)((0 * 4 + ni) * 4 + w) * 256 + lane * 4];
    __syncthreads();   // B1: all xs reads done; Q/K visible

    // ---- V regs -> vt[ch][tok] (overwrites xs space; packed b64)
    {
#pragma unroll
        for (int mi = 0; mi < 4; ++mi) {
            bf16x4 pk;
#pragma unroll
            for (int e = 0; e < 4; ++e) pk[e] = (bf16)vh0[mi][e];
            *(bf16x4*)&vt[((w + 12 - 12) * 16 + lr) * 72 + mi * 16 + lk * 4] = pk;
        }
        if (w < 2) {
#pragma unroll
            for (int mi = 0; mi < 4; ++mi) {
                bf16x4 pk;
#pragma unroll
                for (int e = 0; e < 4; ++e) pk[e] = (bf16)vh1[mi][e];
                *(bf16x4*)&vt[((w + 16 - 12) * 16 + lr) * 72 + mi * 16 + lk * 4] = pk;
            }
        }
    }
    // read Q A-frags (own strip) before P overlays it
    bf16x8 qa[3];
#pragma unroll
    for (int h = 0; h < 3; ++h)
        qa[h] = *(const bf16x8*)&qall[(w * 16 + lr) * 104 + h * 32 + lk * 8];
    __syncthreads();   // B2': vt visible to all waves

    bf16* Pw = (bf16*)(smem + w * 3328);   // [16][72] inside own qall strip

    f32x4 oacc[3][2];
#pragma unroll
    for (int h = 0; h < 3; ++h)
#pragma unroll
        for (int ni = 0; ni < 2; ++ni) oacc[h][ni] = (f32x4){0.f, 0.f, 0.f, 0.f};

#pragma unroll
    for (int h = 0; h < 3; ++h) {
        // S = Q@K^T + bias (bias is the C-operand)
        f32x4 sacc[4];
        const f32x4* bc = (h == 0) ? bias0 : (h == 1) ? bias1 : bias2;
#pragma unroll
        for (int ni = 0; ni < 4; ++ni) {
            bf16x8 kb = *(const bf16x8*)&kall[(ni * 16 + lr) * 104 + h * 32 + lk * 8];
            sacc[ni] = __builtin_amdgcn_mfma_f32_16x16x32_bf16(qa[h], kb, bc[ni], 0, 0, 0);
        }
        // prefetch next head's bias (covered by softmax+PV)
        if (h == 0) {
#pragma unroll
            for (int ni = 0; ni < 4; ++ni)
                bias1[ni] = *(const f32x4*)&biasC[(size_t)((1 * 4 + ni) * 4 + w) * 256 + lane * 4];
        } else if (h == 1) {
#pragma unroll
            for (int ni = 0; ni < 4; ++ni)
                bias2[ni] = *(const f32x4*)&biasC[(size_t)((2 * 4 + ni) * 4 + w) * 256 + lane * 4];
        }
        // softmax: 4 regs local + DPP 16-lane all-reduce; P normalized at write
#pragma unroll
        for (int e = 0; e < 4; ++e) {
            float s0 = sacc[0][e], s1 = sacc[1][e], s2 = sacc[2][e], s3 = sacc[3][e];
            float m = row16_max(fmaxf(fmaxf(s0, s1), fmaxf(s2, s3)));
            float p0 = __expf(s0 - m), p1 = __expf(s1 - m);
            float p2 = __expf(s2 - m), p3 = __expf(s3 - m);
            float s = row16_sum((p0 + p1) + (p2 + p3));
            float inv = __builtin_amdgcn_rcpf(s);
            int rl = lk * 4 + e;
            Pw[rl * 72 + lr]      = (bf16)(p0 * inv);
            Pw[rl * 72 + 16 + lr] = (bf16)(p1 * inv);
            Pw[rl * 72 + 32 + lr] = (bf16)(p2 * inv);
            Pw[rl * 72 + 48 + lr] = (bf16)(p3 * inv);
        }
        CBAR();
        // PV: Ostrip_h += Pstrip @ V_h
#pragma unroll
        for (int kk = 0; kk < 2; ++kk) {
            bf16x8 pa = *(const bf16x8*)&Pw[lr * 72 + kk * 32 + lk * 8];
#pragma unroll
            for (int ni = 0; ni < 2; ++ni) {
                bf16x8 vb = *(const bf16x8*)&vt[(h * 32 + ni * 16 + lr) * 72 + kk * 32 + lk * 8];
                oacc[h][ni] = __builtin_amdgcn_mfma_f32_16x16x32_bf16(pa, vb, oacc[h][ni], 0, 0, 0);
            }
        }
        CBAR();
    }

    // ---- O -> Ost (overlay qall, own strip only)
#pragma unroll
    for (int h = 0; h < 3; ++h)
#pragma unroll
        for (int ni = 0; ni < 2; ++ni)
#pragma unroll
            for (int e = 0; e < 4; ++e)
                Ost[(w * 16 + lk * 4 + e) * 104 + h * 32 + ni * 16 + lr]
                    = (bf16)oacc[h][ni][e];
    __syncthreads();   // B3: Ost visible; kall/vt dead -> fin overlay safe

    // ---- proj: wave w owns ni tiles {w, w+4 (w<2)}; all 4 row strips.
    {
        const int pcnt = (w < 2) ? 2 : 1;
#pragma unroll
        for (int j = 0; j < 2; ++j) {
            if (j < pcnt) {
                const int ni = w + j * 4;
                const float bo = bout[ni * 16 + lr];
                f32x4 pacc[4];
#pragma unroll
                for (int mi = 0; mi < 4; ++mi) pacc[mi] = (f32x4){0.f, 0.f, 0.f, 0.f};
#pragma unroll
                for (int k = 0; k < 3; ++k) {
                    bf16x8 wb = *(const bf16x8*)&woutT[(ni * 16 + lr) * 96 + k * 32 + lk * 8];
#pragma unroll
                    for (int mi = 0; mi < 4; ++mi) {
                        bf16x8 as = *(const bf16x8*)&Ost[(mi * 16 + lr) * 104 + k * 32 + lk * 8];
                        pacc[mi] = __builtin_amdgcn_mfma_f32_16x16x32_bf16(as, wb, pacc[mi], 0, 0, 0);
                    }
                }
#pragma unroll
                for (int mi = 0; mi < 4; ++mi)
#pragma unroll
                    for (int e = 0; e < 4; ++e)
                        fin[(mi * 16 + lk * 4 + e) * 101 + ni * 16 + lr] = pacc[mi][e] + bo;
            }
        }
    }
    __syncthreads();   // B4

    // ---- store [b, c, H, W]; t = lane fixed, channel marches
    {
        const int t = lane;
        if (t < 49) {
            const int off = (row0 + t / 7) * 56 + col0 + t % 7;
            float* ob = out + (size_t)(b * 96 + w * 24) * 3136 + off;
            const float* fr = fin + t * 101 + w * 24;
#pragma unroll
            for (int j = 0; j < 24; ++j)
                ob[(size_t)j * 3136] = fr[j];
        }
    }
}

extern "C" void kernel_launch(void* const* d_in, const int* in_sizes, int n_in,
                              void* d_out, int out_size, void* d_ws, size_t ws_size,
                              hipStream_t stream) {
    const float* x    = (const float*)d_in[0];
    const float* wqkv = (const float*)d_in[1];
    const float* pos  = (const float*)d_in[2];
    const float* wout = (const float*)d_in[3];
    const float* bout = (const float*)d_in[4];
    float* outp = (float*)d_out;

    bf16*  wqkvT = (bf16*)((char*)d_ws + WQKVT_OFF);
    bf16*  woutT = (bf16*)((char*)d_ws + WOUTT_OFF);
    float* biasC = (float*)((char*)d_ws + BIASC_OFF);

    prep<<<dim3(4), dim3(512), 0, stream>>>(wqkv, pos, wout, wqkvT, woutT, biasC);
    winattn<<<dim3(4096), dim3(256), 0, stream>>>(x, bout, wqkvT, woutT,
                                                  biasC, outp);
}